// Round 1
// baseline (4256.242 us; speedup 1.0000x reference)
//
#include <hip/hip_runtime.h>

#define B_ 16
#define N_ 773
#define C_ 768
#define H_ 12
#define D_ 64
#define P_ 64
#define T_ 196
#define M_ 901              // 2P + N
#define K3_ 2304            // 3C
#define GM_ (B_*N_)         // 12368 rows in the big GEMMs

static __device__ __forceinline__ float4 f4zero() { return make_float4(0.f, 0.f, 0.f, 0.f); }

// ---------------------------------------------------------------------------
// Prompt MLP stage 1: h = tanh(emb @ w1^T + b1) for text(e=0) and image(e=1).
// Batch-independent (reference broadcasts emb over B) -> compute once.
// ---------------------------------------------------------------------------
__global__ void prompt_h(const float* __restrict__ te, const float* __restrict__ ie,
                         const float* __restrict__ w1, const float* __restrict__ b1,
                         float* __restrict__ Hb)
{
    int f = blockIdx.x * 256 + threadIdx.x;          // [0, 2*P*C)
    int e = f / (P_ * C_);
    int r = f - e * (P_ * C_);
    int p = r / C_;
    int c = r - p * C_;
    const float* emb = (e ? ie : te) + (size_t)p * C_;
    const float* wr  = w1 + (size_t)c * C_;
    float s = 0.f;
    for (int k = 0; k < C_; k += 4) {
        float4 a = *(const float4*)(emb + k);
        float4 w = *(const float4*)(wr + k);
        s = fmaf(a.x, w.x, s); s = fmaf(a.y, w.y, s);
        s = fmaf(a.z, w.z, s); s = fmaf(a.w, w.w, s);
    }
    Hb[f] = tanhf(s + b1[c]);
}

// ---------------------------------------------------------------------------
// Prompt MLP stage 2: p2 = h @ w2^T + b2  (P x 2C per emb)
// ---------------------------------------------------------------------------
__global__ void prompt_p2(const float* __restrict__ Hb, const float* __restrict__ w2,
                          const float* __restrict__ b2, float* __restrict__ P2)
{
    int f = blockIdx.x * 256 + threadIdx.x;          // [0, 2*P*2C)
    int e = f / (P_ * 2 * C_);
    int r = f - e * (P_ * 2 * C_);
    int p = r / (2 * C_);
    int j = r - p * (2 * C_);
    const float* hr = Hb + ((size_t)e * P_ + p) * C_;
    const float* wr = w2 + (size_t)j * C_;
    float s = 0.f;
    for (int k = 0; k < C_; k += 4) {
        float4 a = *(const float4*)(hr + k);
        float4 w = *(const float4*)(wr + k);
        s = fmaf(a.x, w.x, s); s = fmaf(a.y, w.y, s);
        s = fmaf(a.z, w.z, s); s = fmaf(a.w, w.w, s);
    }
    P2[f] = s + b2[j];
}

// ---------------------------------------------------------------------------
// Scatter prompt K/V into the concatenated KF/VF buffers for every batch.
// Reference reshape is FLAT: kp(B,P,C) -> (B,H,P,D) with
//   flat f = p*C + c  ->  h = f/4096, p2 = (f/64)%64, d = f%64
// text prefix occupies seq [0,P), image prefix seq [P+T, 2P+T).
// ---------------------------------------------------------------------------
__global__ void scatter_prompts(const float* __restrict__ P2,
                                float* __restrict__ KF, float* __restrict__ VF)
{
    int f = blockIdx.x * 256 + threadIdx.x;          // [0, 2*P*C)
    int e = f / (P_ * C_);
    int r = f - e * (P_ * C_);
    int h   = r / (P_ * D_);                         // r / 4096
    int p2i = (r >> 6) & 63;
    int d   = r & 63;
    int p = r / C_;
    int c = r - p * C_;
    const float* row = P2 + ((size_t)e * P_ + p) * (2 * C_);
    float kv = row[c];
    float vv = row[C_ + c];
    int pos = (e == 0) ? p2i : (P_ + T_ + p2i);
    #pragma unroll
    for (int b = 0; b < B_; ++b) {
        size_t idx = (((size_t)b * H_ + h) * M_ + pos) * D_ + d;
        KF[idx] = kv;
        VF[idx] = vv;
    }
}

// ---------------------------------------------------------------------------
// Tiled fp32 GEMM:  O = A(GM x 768) @ W^T(768 x 64*gridDim.y) (+bias)
// MODE 0: proj epilogue -> O0[g*C + j] = acc + b0[j]
// MODE 1: qkv epilogue  -> scatter into Q (pre-scaled by 0.125), KF, VF.
// 64x64 tile, BK=16, 256 threads, 4x4 microtile, LDS k-major pad-68.
// ---------------------------------------------------------------------------
template<int MODE>
__launch_bounds__(256)
__global__ void gemm_tiled(const float* __restrict__ A, const float* __restrict__ W,
                           const float* __restrict__ b0, const float* __restrict__ b1,
                           float* __restrict__ O0, float* __restrict__ O1,
                           float* __restrict__ O2)
{
    __shared__ float As[16][68];
    __shared__ float Ws[16][68];
    const int t  = threadIdx.x;
    const int g0 = blockIdx.x * 64;
    const int j0 = blockIdx.y * 64;
    const int r0 = (t >> 4) << 2;      // 0..60
    const int c0 = (t & 15) << 2;      // 0..60
    const int lm = t >> 2;             // 0..63
    const int lk = (t & 3) << 2;       // 0,4,8,12
    float acc[4][4] = {};
    const bool aval = (g0 + lm) < GM_;
    const float* Ap = A + (size_t)(g0 + lm) * C_ + lk;
    const float* Wp = W + (size_t)(j0 + lm) * C_ + lk;

    for (int k0 = 0; k0 < C_; k0 += 16) {
        float4 a = aval ? *(const float4*)(Ap + k0) : f4zero();
        float4 w = *(const float4*)(Wp + k0);
        __syncthreads();
        As[lk + 0][lm] = a.x; As[lk + 1][lm] = a.y;
        As[lk + 2][lm] = a.z; As[lk + 3][lm] = a.w;
        Ws[lk + 0][lm] = w.x; Ws[lk + 1][lm] = w.y;
        Ws[lk + 2][lm] = w.z; Ws[lk + 3][lm] = w.w;
        __syncthreads();
        #pragma unroll
        for (int kk = 0; kk < 16; ++kk) {
            const float4 av = *(const float4*)&As[kk][r0];
            const float4 wv = *(const float4*)&Ws[kk][c0];
            const float aa[4] = {av.x, av.y, av.z, av.w};
            const float ww[4] = {wv.x, wv.y, wv.z, wv.w};
            #pragma unroll
            for (int rr = 0; rr < 4; ++rr)
                #pragma unroll
                for (int cc = 0; cc < 4; ++cc)
                    acc[rr][cc] = fmaf(aa[rr], ww[cc], acc[rr][cc]);
        }
    }

    if (MODE == 0) {
        #pragma unroll
        for (int rr = 0; rr < 4; ++rr) {
            int g = g0 + r0 + rr;
            if (g >= GM_) break;
            float4 o;
            o.x = acc[rr][0] + b0[j0 + c0 + 0];
            o.y = acc[rr][1] + b0[j0 + c0 + 1];
            o.z = acc[rr][2] + b0[j0 + c0 + 2];
            o.w = acc[rr][3] + b0[j0 + c0 + 3];
            *(float4*)(O0 + (size_t)g * C_ + j0 + c0) = o;
        }
    } else {
        const int which = j0 / C_;                 // 0=q, 1=k, 2=v (tile-uniform)
        const int h = (j0 % C_) / D_;              // tile-uniform
        const int d0 = c0;                         // j0 % 64 == 0
        float bias[4];
        #pragma unroll
        for (int cc = 0; cc < 4; ++cc) {
            int jm = (j0 % C_) + c0 + cc;          // h*64 + d
            bias[cc] = (which == 0) ? b0[jm] : ((which == 2) ? b1[jm] : 0.f);
        }
        #pragma unroll
        for (int rr = 0; rr < 4; ++rr) {
            int g = g0 + r0 + rr;
            if (g >= GM_) break;
            int b = g / N_;
            int n = g - b * N_;
            #pragma unroll
            for (int cc = 0; cc < 4; ++cc) {
                float v = acc[rr][cc] + bias[cc];
                int d = d0 + cc;
                if (which == 0) {
                    O0[(((size_t)b * H_ + h) * N_ + n) * D_ + d] = v * 0.125f; // q*scale, exact
                } else {
                    int pos = n + (n < T_ ? P_ : 2 * P_);
                    float* dst = (which == 1) ? O1 : O2;
                    dst[(((size_t)b * H_ + h) * M_ + pos) * D_ + d] = v;
                }
            }
        }
    }
}

// ---------------------------------------------------------------------------
// Flash-style attention over the concatenated sequence (M=901).
// Block: 16 Q-rows x one (b,h). 256 threads: thread t -> row r=t/16,
// 4-wide column group q4=4*(t%16) (used as mm-group for S, d-group for PV).
// K tile stored transposed in LDS ([d][mm]) for conflict-free S dots.
// ---------------------------------------------------------------------------
__launch_bounds__(256)
__global__ void attn_kernel(const float* __restrict__ Q, const float* __restrict__ KF,
                            const float* __restrict__ VF, const float* __restrict__ rpb,
                            const float* __restrict__ mask, float* __restrict__ ATT)
{
    __shared__ float Qs[16][68];
    __shared__ float Ks[64][68];   // [d][mm]  (transposed)
    __shared__ float Vs[64][68];   // [mm][d]
    __shared__ float Ps[16][68];

    const int t  = threadIdx.x;
    const int r  = t >> 4;             // 0..15
    const int q4 = (t & 15) << 2;      // 0..60
    const int h  = blockIdx.y;
    const int b  = blockIdx.z;
    const int n0 = blockIdx.x * 16;
    const int n  = n0 + r;
    const bool rv = (n < N_);
    const int bh = b * H_ + h;

    {   // load Q rows (pre-scaled by 0.125 already)
        float4 qv = rv ? *(const float4*)(Q + ((size_t)bh * N_ + n) * D_ + q4) : f4zero();
        *(float4*)&Qs[r][q4] = qv;
    }

    float4 acc = f4zero();
    float m_run = -__builtin_inff();
    float l_run = 0.f;

    for (int m0 = 0; m0 < M_; m0 += 64) {
        __syncthreads();   // protect LDS from previous iteration's readers
        #pragma unroll
        for (int i = 0; i < 4; ++i) {
            int mm = i * 16 + (t >> 4);
            int mg = m0 + mm;
            float4 kv, vv;
            if (mg < M_) {
                kv = *(const float4*)(KF + ((size_t)bh * M_ + mg) * D_ + q4);
                vv = *(const float4*)(VF + ((size_t)bh * M_ + mg) * D_ + q4);
            } else {
                kv = f4zero(); vv = f4zero();
            }
            Ks[q4 + 0][mm] = kv.x; Ks[q4 + 1][mm] = kv.y;
            Ks[q4 + 2][mm] = kv.z; Ks[q4 + 3][mm] = kv.w;
            *(float4*)&Vs[mm][q4] = vv;
        }
        __syncthreads();

        // S = (Q*scale) @ K^T for (row r, cols m0+q4..q4+3)
        float4 s = f4zero();
        #pragma unroll
        for (int d = 0; d < 64; d += 4) {
            float4 qq = *(const float4*)&Qs[r][d];
            float4 k0 = *(const float4*)&Ks[d + 0][q4];
            float4 k1 = *(const float4*)&Ks[d + 1][q4];
            float4 k2 = *(const float4*)&Ks[d + 2][q4];
            float4 k3 = *(const float4*)&Ks[d + 3][q4];
            s.x = fmaf(qq.x, k0.x, s.x); s.y = fmaf(qq.x, k0.y, s.y);
            s.z = fmaf(qq.x, k0.z, s.z); s.w = fmaf(qq.x, k0.w, s.w);
            s.x = fmaf(qq.y, k1.x, s.x); s.y = fmaf(qq.y, k1.y, s.y);
            s.z = fmaf(qq.y, k1.z, s.z); s.w = fmaf(qq.y, k1.w, s.w);
            s.x = fmaf(qq.z, k2.x, s.x); s.y = fmaf(qq.z, k2.y, s.y);
            s.z = fmaf(qq.z, k2.z, s.z); s.w = fmaf(qq.z, k2.w, s.w);
            s.x = fmaf(qq.w, k3.x, s.x); s.y = fmaf(qq.w, k3.y, s.y);
            s.z = fmaf(qq.w, k3.z, s.z); s.w = fmaf(qq.w, k3.w, s.w);
        }

        // bias + mask + bounds
        float sv[4] = {s.x, s.y, s.z, s.w};
        #pragma unroll
        for (int i = 0; i < 4; ++i) {
            int mg = m0 + q4 + i;
            float sval = sv[i];
            if (mg >= M_) {
                sval = -__builtin_inff();
            } else if (mg >= P_) {
                int col = -1;
                if (mg < P_ + T_)            col = mg - P_;
                else if (mg >= 2 * P_ + T_)  col = mg - 2 * P_;
                if (col >= 0) {
                    float mk = mask[b * N_ + col];
                    if (mk == 0.f) sval = -__builtin_inff();
                    else sval += rv ? rpb[((size_t)h * N_ + n) * N_ + col] : 0.f;
                }
            }
            sv[i] = sval;
        }

        // online softmax (per-row state replicated across the row's 16 lanes)
        float tm = fmaxf(fmaxf(sv[0], sv[1]), fmaxf(sv[2], sv[3]));
        #pragma unroll
        for (int o = 1; o < 16; o <<= 1) tm = fmaxf(tm, __shfl_xor(tm, o, 64));
        float m_new = fmaxf(m_run, tm);
        float corr = __expf(m_run - m_new);   // first tile: exp(-inf)=0
        float4 p;
        p.x = __expf(sv[0] - m_new); p.y = __expf(sv[1] - m_new);
        p.z = __expf(sv[2] - m_new); p.w = __expf(sv[3] - m_new);
        float psum = p.x + p.y + p.z + p.w;
        #pragma unroll
        for (int o = 1; o < 16; o <<= 1) psum += __shfl_xor(psum, o, 64);
        l_run = l_run * corr + psum;
        acc.x *= corr; acc.y *= corr; acc.z *= corr; acc.w *= corr;
        m_run = m_new;
        *(float4*)&Ps[r][q4] = p;
        __syncthreads();

        // PV: acc(r, d0=q4..q4+3) += P[r][mm] * V[mm][d]
        #pragma unroll 8
        for (int mm = 0; mm < 64; ++mm) {
            float pv = Ps[r][mm];
            float4 vv = *(const float4*)&Vs[mm][q4];
            acc.x = fmaf(pv, vv.x, acc.x);
            acc.y = fmaf(pv, vv.y, acc.y);
            acc.z = fmaf(pv, vv.z, acc.z);
            acc.w = fmaf(pv, vv.w, acc.w);
        }
    }

    if (rv) {
        float inv = 1.f / l_run;
        float4 o = make_float4(acc.x * inv, acc.y * inv, acc.z * inv, acc.w * inv);
        *(float4*)(ATT + (size_t)(b * N_ + n) * C_ + h * D_ + q4) = o;
    }
}

// ---------------------------------------------------------------------------
extern "C" void kernel_launch(void* const* d_in, const int* in_sizes, int n_in,
                              void* d_out, int out_size, void* d_ws, size_t ws_size,
                              hipStream_t stream)
{
    const float* x         = (const float*)d_in[0];
    const float* mask      = (const float*)d_in[1];
    const float* rpb       = (const float*)d_in[2];
    const float* qkv_w     = (const float*)d_in[3];
    const float* q_bias    = (const float*)d_in[4];
    const float* v_bias    = (const float*)d_in[5];
    const float* proj_w    = (const float*)d_in[6];
    const float* proj_b    = (const float*)d_in[7];
    const float* text_emb  = (const float*)d_in[8];
    const float* image_emb = (const float*)d_in[9];
    const float* pp_w1     = (const float*)d_in[10];
    const float* pp_b1     = (const float*)d_in[11];
    const float* pp_w2     = (const float*)d_in[12];
    const float* pp_b2     = (const float*)d_in[13];
    float* out = (float*)d_out;

    float* ws = (float*)d_ws;
    size_t off = 0;
    float* Q   = ws + off; off += (size_t)B_ * H_ * N_ * D_;   // 9,498,624
    float* KF  = ws + off; off += (size_t)B_ * H_ * M_ * D_;   // 11,071,488
    float* VF  = ws + off; off += (size_t)B_ * H_ * M_ * D_;
    float* ATT = ws + off; off += (size_t)B_ * N_ * C_;        // 9,498,624
    float* Hb  = ws + off; off += (size_t)2 * P_ * C_;
    float* P2  = ws + off; off += (size_t)2 * P_ * 2 * C_;
    (void)ws_size; (void)in_sizes; (void)n_in; (void)out_size;

    prompt_h<<<(2 * P_ * C_) / 256, 256, 0, stream>>>(text_emb, image_emb, pp_w1, pp_b1, Hb);
    prompt_p2<<<(2 * P_ * 2 * C_) / 256, 256, 0, stream>>>(Hb, pp_w2, pp_b2, P2);
    scatter_prompts<<<(2 * P_ * C_) / 256, 256, 0, stream>>>(P2, KF, VF);
    gemm_tiled<1><<<dim3((GM_ + 63) / 64, K3_ / 64), 256, 0, stream>>>(
        x, qkv_w, q_bias, v_bias, Q, KF, VF);
    attn_kernel<<<dim3((N_ + 15) / 16, H_, B_), 256, 0, stream>>>(
        Q, KF, VF, rpb, mask, ATT);
    gemm_tiled<0><<<dim3((GM_ + 63) / 64, C_ / 64), 256, 0, stream>>>(
        ATT, proj_w, proj_b, nullptr, out, nullptr, nullptr);
}

// Round 4
// 1759.788 us; speedup vs baseline: 2.4186x; 2.4186x over previous
//
#include <hip/hip_runtime.h>

#define B_ 16
#define N_ 773
#define C_ 768
#define H_ 12
#define D_ 64
#define P_ 64
#define T_ 196
#define M_ 901              // 2P + N
#define K3_ 2304            // 3C
#define GM_ (B_*N_)         // 12368 rows in the big GEMMs
#define VTP_ 960            // padded M for transposed V rows (16B-aligned, covers tile overrun)

typedef __bf16 bf16_t;
typedef __bf16 bf16x8 __attribute__((ext_vector_type(8)));
typedef float f32x4 __attribute__((ext_vector_type(4)));

static __device__ __forceinline__ float4 f4zero() { return make_float4(0.f, 0.f, 0.f, 0.f); }

// split fp32 into bf16 hi/lo (RNE both; residual ~2^-17 rel)
static __device__ __forceinline__ void bsplit(float v, bf16_t& hi, bf16_t& lo) {
    hi = (bf16_t)v;
    lo = (bf16_t)(v - (float)hi);
}

// ---------------------------------------------------------------------------
// Prompt MLP stage 1: h = tanh(emb @ w1^T + b1), text(e=0)/image(e=1), once.
// ---------------------------------------------------------------------------
__global__ void prompt_h(const float* __restrict__ te, const float* __restrict__ ie,
                         const float* __restrict__ w1, const float* __restrict__ b1,
                         float* __restrict__ Hb)
{
    int f = blockIdx.x * 256 + threadIdx.x;          // [0, 2*P*C)
    int e = f / (P_ * C_);
    int r = f - e * (P_ * C_);
    int p = r / C_;
    int c = r - p * C_;
    const float* emb = (e ? ie : te) + (size_t)p * C_;
    const float* wr  = w1 + (size_t)c * C_;
    float s = 0.f;
    for (int k = 0; k < C_; k += 4) {
        float4 a = *(const float4*)(emb + k);
        float4 w = *(const float4*)(wr + k);
        s = fmaf(a.x, w.x, s); s = fmaf(a.y, w.y, s);
        s = fmaf(a.z, w.z, s); s = fmaf(a.w, w.w, s);
    }
    Hb[f] = tanhf(s + b1[c]);
}

// ---------------------------------------------------------------------------
// Prompt MLP stage 2: p2 = h @ w2^T + b2  (P x 2C per emb)
// ---------------------------------------------------------------------------
__global__ void prompt_p2(const float* __restrict__ Hb, const float* __restrict__ w2,
                          const float* __restrict__ b2, float* __restrict__ P2)
{
    int f = blockIdx.x * 256 + threadIdx.x;          // [0, 2*P*2C)
    int e = f / (P_ * 2 * C_);
    int r = f - e * (P_ * 2 * C_);
    int p = r / (2 * C_);
    int j = r - p * (2 * C_);
    const float* hr = Hb + ((size_t)e * P_ + p) * C_;
    const float* wr = w2 + (size_t)j * C_;
    float s = 0.f;
    for (int k = 0; k < C_; k += 4) {
        float4 a = *(const float4*)(hr + k);
        float4 w = *(const float4*)(wr + k);
        s = fmaf(a.x, w.x, s); s = fmaf(a.y, w.y, s);
        s = fmaf(a.z, w.z, s); s = fmaf(a.w, w.w, s);
    }
    P2[f] = s + b2[j];
}

// ---------------------------------------------------------------------------
// Scatter prompt K/V (bf16 hi/lo) into KH/KL [bh][m][d] and VTH/VTL [bh][d][m].
// Reference reshape is FLAT: h = f/4096, p2 = (f/64)%64, d = f%64.
// ---------------------------------------------------------------------------
__global__ void scatter_prompts(const float* __restrict__ P2,
                                bf16_t* __restrict__ KH, bf16_t* __restrict__ KL,
                                bf16_t* __restrict__ VTH, bf16_t* __restrict__ VTL)
{
    int f = blockIdx.x * 256 + threadIdx.x;          // [0, 2*P*C)
    int e = f / (P_ * C_);
    int r = f - e * (P_ * C_);
    int h   = r / (P_ * D_);
    int p2i = (r >> 6) & 63;
    int d   = r & 63;
    int p = r / C_;
    int c = r - p * C_;
    const float* row = P2 + ((size_t)e * P_ + p) * (2 * C_);
    float kv = row[c];
    float vv = row[C_ + c];
    int pos = (e == 0) ? p2i : (P_ + T_ + p2i);
    bf16_t kh, kl, vh, vl;
    bsplit(kv, kh, kl);
    bsplit(vv, vh, vl);
    #pragma unroll
    for (int b = 0; b < B_; ++b) {
        size_t bh = (size_t)b * H_ + h;
        size_t kidx = (bh * M_ + pos) * D_ + d;
        KH[kidx] = kh; KL[kidx] = kl;
        size_t vidx = bh * (D_ * VTP_) + (size_t)d * VTP_ + pos;
        VTH[vidx] = vh; VTL[vidx] = vl;
    }
}

// ---------------------------------------------------------------------------
// Tiled fp32 GEMM:  O = A(GM x 768) @ W^T(768 x 64*gridDim.y) (+bias)
// MODE 0: proj epilogue -> O0[g*C + j] = acc + b0[j]
// MODE 1: qkv epilogue  -> bf16 hi/lo split into QH/QL (pre-scaled 0.125),
//                          KH/KL [bh][m][d], VTH/VTL [bh][d][m] (transposed).
// ---------------------------------------------------------------------------
template<int MODE>
__launch_bounds__(256)
__global__ void gemm_tiled(const float* __restrict__ A, const float* __restrict__ W,
                           const float* __restrict__ b0, const float* __restrict__ b1,
                           float* __restrict__ O0,
                           bf16_t* __restrict__ QH, bf16_t* __restrict__ QL,
                           bf16_t* __restrict__ KH, bf16_t* __restrict__ KL,
                           bf16_t* __restrict__ VTH, bf16_t* __restrict__ VTL)
{
    __shared__ float As[16][68];
    __shared__ float Ws[16][68];
    const int t  = threadIdx.x;
    const int g0 = blockIdx.x * 64;
    const int j0 = blockIdx.y * 64;
    const int r0 = (t >> 4) << 2;
    const int c0 = (t & 15) << 2;
    const int lm = t >> 2;
    const int lk = (t & 3) << 2;
    float acc[4][4] = {};
    const bool aval = (g0 + lm) < GM_;
    const float* Ap = A + (size_t)(g0 + lm) * C_ + lk;
    const float* Wp = W + (size_t)(j0 + lm) * C_ + lk;

    for (int k0 = 0; k0 < C_; k0 += 16) {
        float4 a = aval ? *(const float4*)(Ap + k0) : f4zero();
        float4 w = *(const float4*)(Wp + k0);
        __syncthreads();
        As[lk + 0][lm] = a.x; As[lk + 1][lm] = a.y;
        As[lk + 2][lm] = a.z; As[lk + 3][lm] = a.w;
        Ws[lk + 0][lm] = w.x; Ws[lk + 1][lm] = w.y;
        Ws[lk + 2][lm] = w.z; Ws[lk + 3][lm] = w.w;
        __syncthreads();
        #pragma unroll
        for (int kk = 0; kk < 16; ++kk) {
            const float4 av = *(const float4*)&As[kk][r0];
            const float4 wv = *(const float4*)&Ws[kk][c0];
            const float aa[4] = {av.x, av.y, av.z, av.w};
            const float ww[4] = {wv.x, wv.y, wv.z, wv.w};
            #pragma unroll
            for (int rr = 0; rr < 4; ++rr)
                #pragma unroll
                for (int cc = 0; cc < 4; ++cc)
                    acc[rr][cc] = fmaf(aa[rr], ww[cc], acc[rr][cc]);
        }
    }

    if (MODE == 0) {
        #pragma unroll
        for (int rr = 0; rr < 4; ++rr) {
            int g = g0 + r0 + rr;
            if (g >= GM_) break;
            float4 o;
            o.x = acc[rr][0] + b0[j0 + c0 + 0];
            o.y = acc[rr][1] + b0[j0 + c0 + 1];
            o.z = acc[rr][2] + b0[j0 + c0 + 2];
            o.w = acc[rr][3] + b0[j0 + c0 + 3];
            *(float4*)(O0 + (size_t)g * C_ + j0 + c0) = o;
        }
    } else {
        const int which = j0 / C_;                 // 0=q, 1=k, 2=v (tile-uniform)
        const int hh = (j0 % C_) / D_;             // tile-uniform
        float bias[4];
        #pragma unroll
        for (int cc = 0; cc < 4; ++cc) {
            int jm = (j0 % C_) + c0 + cc;
            bias[cc] = (which == 0) ? b0[jm] : ((which == 2) ? b1[jm] : 0.f);
        }
        #pragma unroll
        for (int rr = 0; rr < 4; ++rr) {
            int g = g0 + r0 + rr;
            if (g >= GM_) break;
            int b = g / N_;
            int n = g - b * N_;
            size_t bh = (size_t)b * H_ + hh;
            #pragma unroll
            for (int cc = 0; cc < 4; ++cc) {
                float v = acc[rr][cc] + bias[cc];
                int d = c0 + cc;
                if (which == 0) {
                    float q = v * 0.125f;          // exact pow2 scale
                    bf16_t hi, lo; bsplit(q, hi, lo);
                    size_t idx = (bh * N_ + n) * D_ + d;
                    QH[idx] = hi; QL[idx] = lo;
                } else {
                    int pos = n + (n < T_ ? P_ : 2 * P_);
                    bf16_t hi, lo; bsplit(v, hi, lo);
                    if (which == 1) {
                        size_t idx = (bh * M_ + pos) * D_ + d;
                        KH[idx] = hi; KL[idx] = lo;
                    } else {
                        size_t idx = bh * (D_ * VTP_) + (size_t)d * VTP_ + pos;
                        VTH[idx] = hi; VTL[idx] = lo;
                    }
                }
            }
        }
    }
}

// ---------------------------------------------------------------------------
// MFMA flash attention. Block = 64 Q-rows = 4 waves x 16 rows. K-tile = 64.
// S^T = K.Q^T via mfma_f32_16x16x32_bf16 (bf16x3 split), online softmax
// fully in-register (q-row lives at lane&15), P redistributed to PV A-frags
// via __shfl, PV accumulates fp32.
// All A/B fragments use the consistent addressing row/col=lane&15,
// k-slot = 8*(lane>>4)+j  (any HW k-permutation cancels when applied to
// both operands). C/D layout: col=lane&15, row=4*(lane>>4)+reg (verified).
// ---------------------------------------------------------------------------
__launch_bounds__(256)
__global__ void attn_mfma(const bf16_t* __restrict__ QH, const bf16_t* __restrict__ QL,
                          const bf16_t* __restrict__ KH, const bf16_t* __restrict__ KL,
                          const bf16_t* __restrict__ VTH, const bf16_t* __restrict__ VTL,
                          const float* __restrict__ rpb, const float* __restrict__ mask,
                          float* __restrict__ ATT)
{
    // 64x64 bf16 tiles, rows 128B, 16B chunks XOR-swizzled by row&7
    __shared__ __align__(16) bf16_t sKh[4096], sKl[4096], sVh[4096], sVl[4096];

    const int t    = threadIdx.x;
    const int w    = t >> 6;            // wave 0..3
    const int lane = t & 63;
    const int G    = lane >> 4;         // k-slot group
    const int q16  = lane & 15;
    const int h  = blockIdx.y;
    const int b  = blockIdx.z;
    const int bh = b * H_ + h;
    const int n0 = blockIdx.x * 64;
    const int nrow = min(n0 + w * 16 + q16, N_ - 1);   // this lane's q-row (clamped)

    // Q B-fragments (hi/lo, 2 d-chunks), register-resident
    bf16x8 qfh[2], qfl[2];
    {
        const size_t qb = ((size_t)bh * N_ + nrow) * D_ + 8 * G;
        #pragma unroll
        for (int dc = 0; dc < 2; ++dc) {
            qfh[dc] = *(const bf16x8*)(QH + qb + 32 * dc);
            qfl[dc] = *(const bf16x8*)(QL + qb + 32 * dc);
        }
    }

    const float* rpbrow = rpb + ((size_t)h * N_ + nrow) * N_;
    const float* mrow   = mask + (size_t)b * N_;

    f32x4 o[4] = {};                    // O accum: [d-tile], row=4G+v, col(d)=16*dt+q16
    float m_run = -__builtin_inff();
    float l_run = 0.f;

    for (int m0 = 0; m0 < M_; m0 += 64) {
        __syncthreads();
        // ---- stage K/V tile (hi/lo), XOR-swizzled 16B chunks ----
        #pragma unroll
        for (int r = 0; r < 2; ++r) {
            const int id = t + 256 * r;       // 0..511
            const int mm = id >> 3;           // row (m for K, d for VT)
            const int ch = id & 7;            // 16B chunk
            const int swz = ((ch ^ (mm & 7)) << 3);
            const size_t kg = (size_t)bh * ((size_t)M_ * D_) + (size_t)(m0 + mm) * D_ + ch * 8;
            const size_t vg = (size_t)bh * (D_ * VTP_) + (size_t)mm * VTP_ + m0 + ch * 8;
            *(uint4*)&sKh[mm * 64 + swz] = *(const uint4*)(KH + kg);
            *(uint4*)&sKl[mm * 64 + swz] = *(const uint4*)(KL + kg);
            *(uint4*)&sVh[mm * 64 + swz] = *(const uint4*)(VTH + vg);
            *(uint4*)&sVl[mm * 64 + swz] = *(const uint4*)(VTL + vg);
        }
        __syncthreads();

        // ---- S^T = K.Q^T : 4 m-tiles x 2 d-chunks x 3 combos ----
        f32x4 s[4] = {};
        #pragma unroll
        for (int tt = 0; tt < 4; ++tt) {
            const int row = tt * 16 + q16;
            #pragma unroll
            for (int dc = 0; dc < 2; ++dc) {
                const int off = row * 64 + (((4 * dc + G) ^ (lane & 7)) << 3);
                bf16x8 kh = *(const bf16x8*)&sKh[off];
                bf16x8 kl = *(const bf16x8*)&sKl[off];
                s[tt] = __builtin_amdgcn_mfma_f32_16x16x32_bf16(kh, qfh[dc], s[tt], 0, 0, 0);
                s[tt] = __builtin_amdgcn_mfma_f32_16x16x32_bf16(kh, qfl[dc], s[tt], 0, 0, 0);
                s[tt] = __builtin_amdgcn_mfma_f32_16x16x32_bf16(kl, qfh[dc], s[tt], 0, 0, 0);
            }
        }

        // ---- bias + mask (lane holds S[q=q16][m = m0+16t+4G+v]) ----
        #pragma unroll
        for (int tt = 0; tt < 4; ++tt) {
            const int mbase = m0 + tt * 16 + 4 * G;   // 4-aligned; regions don't straddle
            if (mbase >= M_) {
                s[tt][0] = s[tt][1] = s[tt][2] = s[tt][3] = -__builtin_inff();
            } else if (!(mbase < P_ || (mbase >= P_ + T_ && mbase < 2 * P_ + T_))) {
                const int col0 = mbase - ((mbase < P_ + T_) ? P_ : 2 * P_);
                #pragma unroll
                for (int v = 0; v < 4; ++v) {
                    const int m = mbase + v;
                    if (m >= M_) { s[tt][v] = -__builtin_inff(); }
                    else {
                        const int col = col0 + v;
                        const float mk = mrow[col];
                        s[tt][v] = (mk != 0.f) ? (s[tt][v] + rpbrow[col]) : -__builtin_inff();
                    }
                }
            }
        }

        // ---- online softmax (row state replicated across the 4 G-copies of q16) ----
        float tmax = -__builtin_inff();
        #pragma unroll
        for (int tt = 0; tt < 4; ++tt)
            #pragma unroll
            for (int v = 0; v < 4; ++v) tmax = fmaxf(tmax, s[tt][v]);
        tmax = fmaxf(tmax, __shfl_xor(tmax, 16, 64));
        tmax = fmaxf(tmax, __shfl_xor(tmax, 32, 64));
        const float m_new = fmaxf(m_run, tmax);
        const float corr  = __expf(m_run - m_new);    // first tile: exp(-inf)=0
        float lsum = 0.f;
        #pragma unroll
        for (int tt = 0; tt < 4; ++tt)
            #pragma unroll
            for (int v = 0; v < 4; ++v) {
                const float p = __expf(s[tt][v] - m_new);
                s[tt][v] = p;                          // s now holds P
                lsum += p;
            }
        lsum += __shfl_xor(lsum, 16, 64);
        lsum += __shfl_xor(lsum, 32, 64);
        l_run = l_run * corr + lsum;
        m_run = m_new;
        float cr[4];
        #pragma unroll
        for (int v = 0; v < 4; ++v) cr[v] = __shfl(corr, 4 * G + v, 64);
        #pragma unroll
        for (int dt = 0; dt < 4; ++dt)
            #pragma unroll
            for (int v = 0; v < 4; ++v) o[dt][v] *= cr[v];

        // ---- PV: redistribute P (shfl) into A-frags, 2 m-chunks ----
        #pragma unroll
        for (int c = 0; c < 2; ++c) {
            bf16x8 pah, pal;
            #pragma unroll
            for (int j = 0; j < 8; ++j) {
                const int srcLane = q16 + 16 * (2 * (G & 1) + (j >> 2));
                const float va = __shfl(s[2 * c][j & 3],     srcLane, 64);
                const float vb = __shfl(s[2 * c + 1][j & 3], srcLane, 64);
                const float val = (G < 2) ? va : vb;
                const bf16_t hh2 = (bf16_t)val;
                pah[j] = hh2;
                pal[j] = (bf16_t)(val - (float)hh2);
            }
            #pragma unroll
            for (int dt = 0; dt < 4; ++dt) {
                const int drow = dt * 16 + q16;
                const int off = drow * 64 + (((4 * c + G) ^ (lane & 7)) << 3);
                bf16x8 vh = *(const bf16x8*)&sVh[off];
                bf16x8 vl = *(const bf16x8*)&sVl[off];
                o[dt] = __builtin_amdgcn_mfma_f32_16x16x32_bf16(pah, vh, o[dt], 0, 0, 0);
                o[dt] = __builtin_amdgcn_mfma_f32_16x16x32_bf16(pah, vl, o[dt], 0, 0, 0);
                o[dt] = __builtin_amdgcn_mfma_f32_16x16x32_bf16(pal, vh, o[dt], 0, 0, 0);
            }
        }
    }

    // ---- epilogue: divide by l_run (state at lane q16 == row) and store ----
    float linv[4];
    #pragma unroll
    for (int v = 0; v < 4; ++v) linv[v] = 1.f / __shfl(l_run, 4 * G + v, 64);
    const int nb = n0 + w * 16;
    #pragma unroll
    for (int dt = 0; dt < 4; ++dt) {
        #pragma unroll
        for (int v = 0; v < 4; ++v) {
            const int n = nb + 4 * G + v;
            if (n < N_)
                ATT[((size_t)b * N_ + n) * C_ + h * D_ + dt * 16 + q16] = o[dt][v] * linv[v];
        }
    }
}

// ---------------------------------------------------------------------------
extern "C" void kernel_launch(void* const* d_in, const int* in_sizes, int n_in,
                              void* d_out, int out_size, void* d_ws, size_t ws_size,
                              hipStream_t stream)
{
    const float* x         = (const float*)d_in[0];
    const float* mask      = (const float*)d_in[1];
    const float* rpb       = (const float*)d_in[2];
    const float* qkv_w     = (const float*)d_in[3];
    const float* q_bias    = (const float*)d_in[4];
    const float* v_bias    = (const float*)d_in[5];
    const float* proj_w    = (const float*)d_in[6];
    const float* proj_b    = (const float*)d_in[7];
    const float* text_emb  = (const float*)d_in[8];
    const float* image_emb = (const float*)d_in[9];
    const float* pp_w1     = (const float*)d_in[10];
    const float* pp_b1     = (const float*)d_in[11];
    const float* pp_w2     = (const float*)d_in[12];
    const float* pp_b2     = (const float*)d_in[13];
    float* out = (float*)d_out;

    float* ws = (float*)d_ws;
    size_t off = 0;
    const size_t Q_ELT  = (size_t)B_ * H_ * N_ * D_;            // 9,498,624 bf16
    const size_t K_ELT  = (size_t)B_ * H_ * M_ * D_ + 8192;     // + slack for tile overrun
    const size_t VT_ELT = (size_t)B_ * H_ * D_ * VTP_;          // 11,796,480 bf16
    bf16_t* QH  = (bf16_t*)(ws + off); off += Q_ELT / 2;
    bf16_t* QL  = (bf16_t*)(ws + off); off += Q_ELT / 2;
    bf16_t* KH  = (bf16_t*)(ws + off); off += K_ELT / 2;
    bf16_t* KL  = (bf16_t*)(ws + off); off += K_ELT / 2;
    bf16_t* VTH = (bf16_t*)(ws + off); off += VT_ELT / 2;
    bf16_t* VTL = (bf16_t*)(ws + off); off += VT_ELT / 2;
    float*  ATT = ws + off;            off += (size_t)B_ * N_ * C_;
    float*  Hb  = ws + off;            off += (size_t)2 * P_ * C_;
    float*  P2  = ws + off;            off += (size_t)2 * P_ * 2 * C_;
    (void)ws_size; (void)in_sizes; (void)n_in; (void)out_size;

    prompt_h<<<(2 * P_ * C_) / 256, 256, 0, stream>>>(text_emb, image_emb, pp_w1, pp_b1, Hb);
    prompt_p2<<<(2 * P_ * 2 * C_) / 256, 256, 0, stream>>>(Hb, pp_w2, pp_b2, P2);
    scatter_prompts<<<(2 * P_ * C_) / 256, 256, 0, stream>>>(P2, KH, KL, VTH, VTL);
    gemm_tiled<1><<<dim3((GM_ + 63) / 64, K3_ / 64), 256, 0, stream>>>(
        x, qkv_w, q_bias, v_bias, nullptr, QH, QL, KH, KL, VTH, VTL);
    attn_mfma<<<dim3((N_ + 63) / 64, H_, B_), 256, 0, stream>>>(
        QH, QL, KH, KL, VTH, VTL, rpb, mask, ATT);
    gemm_tiled<0><<<dim3((GM_ + 63) / 64, C_ / 64), 256, 0, stream>>>(
        ATT, proj_w, proj_b, nullptr, out,
        nullptr, nullptr, nullptr, nullptr, nullptr, nullptr);
}

// Round 6
// 883.721 us; speedup vs baseline: 4.8163x; 1.9913x over previous
//
#include <hip/hip_runtime.h>

#define B_ 16
#define N_ 773
#define C_ 768
#define H_ 12
#define D_ 64
#define P_ 64
#define T_ 196
#define M_ 901              // 2P + N
#define GM_ (B_*N_)         // 12368 rows in the big GEMMs
#define GMP_ 12416          // 97*128, padded rows for 128-tall GEMM tiles
#define VTP_ 960            // padded M for transposed V rows (16B-aligned, covers tile overrun)
#define MP_ 960             // padded M for rpb/mask bias tables

typedef __bf16 bf16_t;
typedef __bf16 bf16x8 __attribute__((ext_vector_type(8)));
typedef __bf16 bf16x4_t __attribute__((ext_vector_type(4)));
typedef float f32x4 __attribute__((ext_vector_type(4)));

// global_load_lds, 16B per lane; LDS dest = wave-uniform base + lane*16 (linear),
// global src is per-lane (pre-swizzled there).
#define GLOAD_LDS16(gptr, lptr) \
  __builtin_amdgcn_global_load_lds((const __attribute__((address_space(1))) uint32_t*)(const void*)(gptr), \
                                   (__attribute__((address_space(3))) uint32_t*)(void*)(lptr), 16, 0, 0)

static __device__ __forceinline__ void bsplit(float v, bf16_t& hi, bf16_t& lo) {
    hi = (bf16_t)v;
    lo = (bf16_t)(v - (float)hi);
}

// ---------------------------------------------------------------------------
// fp32 -> bf16 hi/lo split, 4 elems/thread
// ---------------------------------------------------------------------------
__global__ void split4(const float* __restrict__ src, bf16_t* __restrict__ Hd,
                       bf16_t* __restrict__ Ld, int n4)
{
    int i = blockIdx.x * 256 + threadIdx.x;
    if (i >= n4) return;
    float4 v = ((const float4*)src)[i];
    bf16_t h0, l0, h1, l1, h2, l2, h3, l3;
    bsplit(v.x, h0, l0); bsplit(v.y, h1, l1);
    bsplit(v.z, h2, l2); bsplit(v.w, h3, l3);
    bf16x4_t h = {h0, h1, h2, h3};
    bf16x4_t l = {l0, l1, l2, l3};
    *(bf16x4_t*)(Hd + 4 * (size_t)i) = h;
    *(bf16x4_t*)(Ld + 4 * (size_t)i) = l;
}

// ---------------------------------------------------------------------------
// Padded rpb table: RPBP[h][n][m] for m in [0,960): 0 on prefix cols,
// rpb on text/img cols, -inf on m>=901 (handles M-tail in attn uniformly).
// ---------------------------------------------------------------------------
__global__ void build_rpbp(const float* __restrict__ rpb, float* __restrict__ RPBP)
{
    int idx = blockIdx.x * 256 + threadIdx.x;      // < H*N*960
    int m  = idx % MP_;
    int hn = idx / MP_;
    float v;
    if (m >= M_)              v = -__builtin_inff();
    else if (m < P_)          v = 0.f;
    else if (m < P_ + T_)     v = rpb[(size_t)hn * N_ + (m - P_)];
    else if (m < 2*P_ + T_)   v = 0.f;
    else                      v = rpb[(size_t)hn * N_ + (m - 2*P_)];
    RPBP[idx] = v;
}

// Mask bias rows: MB[b][m] = 0 (visible) or -inf (masked); 0 on pads/prefix.
__global__ void build_mb(const float* __restrict__ mask, float* __restrict__ MB)
{
    int idx = blockIdx.x * 256 + threadIdx.x;      // < B*960
    int m = idx % MP_;
    int b = idx / MP_;
    float v = 0.f;
    if (m >= P_ && m < P_ + T_)
        v = (mask[b * N_ + (m - P_)] != 0.f) ? 0.f : -__builtin_inff();
    else if (m >= 2*P_ + T_ && m < M_)
        v = (mask[b * N_ + (m - 2*P_)] != 0.f) ? 0.f : -__builtin_inff();
    MB[idx] = v;
}

// ---------------------------------------------------------------------------
// Prompt MLP stage 1: h = tanh(emb @ w1^T + b1), text(e=0)/image(e=1), once.
// ---------------------------------------------------------------------------
__global__ void prompt_h(const float* __restrict__ te, const float* __restrict__ ie,
                         const float* __restrict__ w1, const float* __restrict__ b1,
                         float* __restrict__ Hb)
{
    int f = blockIdx.x * 256 + threadIdx.x;          // [0, 2*P*C)
    int e = f / (P_ * C_);
    int r = f - e * (P_ * C_);
    int p = r / C_;
    int c = r - p * C_;
    const float* emb = (e ? ie : te) + (size_t)p * C_;
    const float* wr  = w1 + (size_t)c * C_;
    float s = 0.f;
    for (int k = 0; k < C_; k += 4) {
        float4 a = *(const float4*)(emb + k);
        float4 w = *(const float4*)(wr + k);
        s = fmaf(a.x, w.x, s); s = fmaf(a.y, w.y, s);
        s = fmaf(a.z, w.z, s); s = fmaf(a.w, w.w, s);
    }
    Hb[f] = tanhf(s + b1[c]);
}

// ---------------------------------------------------------------------------
// Prompt MLP stage 2: p2 = h @ w2^T + b2  (P x 2C per emb)
// ---------------------------------------------------------------------------
__global__ void prompt_p2(const float* __restrict__ Hb, const float* __restrict__ w2,
                          const float* __restrict__ b2, float* __restrict__ P2)
{
    int f = blockIdx.x * 256 + threadIdx.x;          // [0, 2*P*2C)
    int e = f / (P_ * 2 * C_);
    int r = f - e * (P_ * 2 * C_);
    int p = r / (2 * C_);
    int j = r - p * (2 * C_);
    const float* hr = Hb + ((size_t)e * P_ + p) * C_;
    const float* wr = w2 + (size_t)j * C_;
    float s = 0.f;
    for (int k = 0; k < C_; k += 4) {
        float4 a = *(const float4*)(hr + k);
        float4 w = *(const float4*)(wr + k);
        s = fmaf(a.x, w.x, s); s = fmaf(a.y, w.y, s);
        s = fmaf(a.z, w.z, s); s = fmaf(a.w, w.w, s);
    }
    P2[f] = s + b2[j];
}

// ---------------------------------------------------------------------------
// Scatter prompt K/V (bf16 hi/lo) into KH/KL [bh][m][d] and VTH/VTL [bh][d][m].
// Reference reshape is FLAT: h = f/4096, p2 = (f/64)%64, d = f%64.
// ---------------------------------------------------------------------------
__global__ void scatter_prompts(const float* __restrict__ P2,
                                bf16_t* __restrict__ KH, bf16_t* __restrict__ KL,
                                bf16_t* __restrict__ VTH, bf16_t* __restrict__ VTL)
{
    int f = blockIdx.x * 256 + threadIdx.x;          // [0, 2*P*C)
    int e = f / (P_ * C_);
    int r = f - e * (P_ * C_);
    int h   = r / (P_ * D_);
    int p2i = (r >> 6) & 63;
    int d   = r & 63;
    int p = r / C_;
    int c = r - p * C_;
    const float* row = P2 + ((size_t)e * P_ + p) * (2 * C_);
    float kv = row[c];
    float vv = row[C_ + c];
    int pos = (e == 0) ? p2i : (P_ + T_ + p2i);
    bf16_t kh, kl, vh, vl;
    bsplit(kv, kh, kl);
    bsplit(vv, vh, vl);
    #pragma unroll
    for (int b = 0; b < B_; ++b) {
        size_t bh = (size_t)b * H_ + h;
        size_t kidx = (bh * M_ + pos) * D_ + d;
        KH[kidx] = kh; KL[kidx] = kl;
        size_t vidx = bh * (D_ * VTP_) + (size_t)d * VTP_ + pos;
        VTH[vidx] = vh; VTL[vidx] = vl;
    }
}

// ---------------------------------------------------------------------------
// MFMA bf16x3 GEMM:  C = A(GMP x 768) @ W^T(NC x 768) (+bias), fp32 accuracy.
// Block 128x128, BK=64, 4 waves (2x2), wave tile 64x64 (4x4 16x16 frags).
// LDS: 64KB (A hi/lo + W hi/lo, 128x64 bf16 each), 128B rows, chunk XOR-swizzle
// by row&7 applied on the GLOBAL source (LDS dest linear for global_load_lds).
// Fragment conventions identical to attn (verified): operand row = lane&15,
// k-slot = 8*(lane>>4)+j; D: row=4*(lane>>4)+reg (1st operand), col=lane&15.
// MODE 0: proj -> out[g*C+j] = acc + b0[j]
// MODE 1: qkv  -> scatter bf16 hi/lo into Q (x0.125), K [bh][m][d], VT [bh][d][m]
// ---------------------------------------------------------------------------
template<int MODE>
__launch_bounds__(256)
__global__ void gemm_mfma(const bf16_t* __restrict__ AH, const bf16_t* __restrict__ AL,
                          const bf16_t* __restrict__ WH, const bf16_t* __restrict__ WL,
                          const float* __restrict__ b0, const float* __restrict__ b1,
                          float* __restrict__ O0,
                          bf16_t* __restrict__ QH, bf16_t* __restrict__ QL,
                          bf16_t* __restrict__ KH, bf16_t* __restrict__ KL,
                          bf16_t* __restrict__ VTH, bf16_t* __restrict__ VTL)
{
    __shared__ __align__(16) bf16_t sAh[8192], sAl[8192], sWh[8192], sWl[8192];

    const int t    = threadIdx.x;
    const int lane = t & 63;
    const int wv   = t >> 6;           // wave 0..3
    const int wrow = wv >> 1;          // 0..1
    const int wcol = wv & 1;           // 0..1
    const int G    = lane >> 4;
    const int q16  = lane & 15;
    const int g0   = blockIdx.x * 128;
    const int j0   = blockIdx.y * 128;

    // staging geometry: slot = i*256 + t covers (row = slot>>3, chunkpos = slot&7)
    const int srow0 = t >> 3;          // rows 0..31 at i=0; +32 per issue
    const int scp   = t & 7;

    f32x4 acc[4][4] = {};              // [ar][wc]

    for (int kt = 0; kt < 12; ++kt) {
        const int k0 = kt * 64;
        __syncthreads();
        const bf16_t* Ah = AH + (size_t)g0 * 768 + k0;
        const bf16_t* Al = AL + (size_t)g0 * 768 + k0;
        const bf16_t* Wh = WH + (size_t)j0 * 768 + k0;
        const bf16_t* Wl = WL + (size_t)j0 * 768 + k0;
        #pragma unroll
        for (int i = 0; i < 4; ++i) {
            const int row = srow0 + 32 * i;
            const int c   = scp ^ (row & 7);            // pre-swizzled global chunk
            const size_t gofs = (size_t)row * 768 + c * 8;
            const int lofs = (i * 256 + t) * 8;         // linear LDS (elements)
            GLOAD_LDS16(Ah + gofs, &sAh[lofs]);
            GLOAD_LDS16(Al + gofs, &sAl[lofs]);
            GLOAD_LDS16(Wh + gofs, &sWh[lofs]);
            GLOAD_LDS16(Wl + gofs, &sWl[lofs]);
        }
        __syncthreads();   // compiler drains vmcnt here -> staged data visible

        #pragma unroll
        for (int kc = 0; kc < 2; ++kc) {
            bf16x8 ah[4], al[4], wh[4], wl[4];
            #pragma unroll
            for (int i = 0; i < 4; ++i) {
                const int ra = wrow * 64 + i * 16 + q16;
                const int oa = ra * 64 + ((4 * kc + G) ^ (ra & 7)) * 8;
                ah[i] = *(const bf16x8*)&sAh[oa];
                al[i] = *(const bf16x8*)&sAl[oa];
                const int rw = wcol * 64 + i * 16 + q16;
                const int ow = rw * 64 + ((4 * kc + G) ^ (rw & 7)) * 8;
                wh[i] = *(const bf16x8*)&sWh[ow];
                wl[i] = *(const bf16x8*)&sWl[ow];
            }
            #pragma unroll
            for (int a = 0; a < 4; ++a)
                #pragma unroll
                for (int wc = 0; wc < 4; ++wc) {
                    acc[a][wc] = __builtin_amdgcn_mfma_f32_16x16x32_bf16(ah[a], wh[wc], acc[a][wc], 0, 0, 0);
                    acc[a][wc] = __builtin_amdgcn_mfma_f32_16x16x32_bf16(ah[a], wl[wc], acc[a][wc], 0, 0, 0);
                    acc[a][wc] = __builtin_amdgcn_mfma_f32_16x16x32_bf16(al[a], wh[wc], acc[a][wc], 0, 0, 0);
                }
        }
    }

    if (MODE == 0) {
        #pragma unroll
        for (int wc = 0; wc < 4; ++wc) {
            const int j = j0 + wcol * 64 + wc * 16 + q16;
            const float bj = b0[j];
            #pragma unroll
            for (int a = 0; a < 4; ++a)
                #pragma unroll
                for (int v = 0; v < 4; ++v) {
                    const int g = g0 + wrow * 64 + a * 16 + 4 * G + v;
                    if (g < GM_) O0[(size_t)g * C_ + j] = acc[a][wc][v] + bj;
                }
        }
    } else {
        const int which = j0 / C_;                    // 0=q,1=k,2=v (128 | 768)
        const int jm0   = j0 - which * C_;
        #pragma unroll
        for (int wc = 0; wc < 4; ++wc) {
            const int jm = jm0 + wcol * 64 + wc * 16 + q16;
            const int hh = jm >> 6;
            const int d  = jm & 63;
            const float bias = (which == 0) ? b0[jm] : ((which == 2) ? b1[jm] : 0.f);
            #pragma unroll
            for (int a = 0; a < 4; ++a)
                #pragma unroll
                for (int v = 0; v < 4; ++v) {
                    const int g = g0 + wrow * 64 + a * 16 + 4 * G + v;
                    if (g >= GM_) continue;
                    const int bb = g / N_;
                    const int n  = g - bb * N_;
                    const size_t bh = (size_t)bb * H_ + hh;
                    float val = acc[a][wc][v] + bias;
                    bf16_t hi, lo;
                    if (which == 0) {
                        bsplit(val * 0.125f, hi, lo);
                        const size_t idx = (bh * N_ + n) * D_ + d;
                        QH[idx] = hi; QL[idx] = lo;
                    } else {
                        const int pos = n + (n < T_ ? P_ : 2 * P_);
                        bsplit(val, hi, lo);
                        if (which == 1) {
                            const size_t idx = (bh * M_ + pos) * D_ + d;
                            KH[idx] = hi; KL[idx] = lo;
                        } else {
                            const size_t idx = bh * (D_ * VTP_) + (size_t)d * VTP_ + pos;
                            VTH[idx] = hi; VTL[idx] = lo;
                        }
                    }
                }
        }
    }
}

// ---------------------------------------------------------------------------
// MFMA flash attention (verified structure) + this round:
//  - bias/mask via padded RPBP/MB tables (aligned float4, no branches)
//  - T14 async-stage: prefetch next K/V tile into regs during compute;
//    barrier2 = lgkmcnt(0)-only wait + raw s_barrier (prefetch vmcnt survives)
//  - epilogue emits bf16 hi/lo (feeds MFMA proj GEMM)
// ---------------------------------------------------------------------------
__launch_bounds__(256)
__global__ void attn_mfma(const bf16_t* __restrict__ QH, const bf16_t* __restrict__ QL,
                          const bf16_t* __restrict__ KH, const bf16_t* __restrict__ KL,
                          const bf16_t* __restrict__ VTH, const bf16_t* __restrict__ VTL,
                          const float* __restrict__ RPBP, const float* __restrict__ MBp,
                          bf16_t* __restrict__ ATTH, bf16_t* __restrict__ ATTL)
{
    __shared__ __align__(16) bf16_t sKh[4096], sKl[4096], sVh[4096], sVl[4096];

    const int t    = threadIdx.x;
    const int w    = t >> 6;
    const int lane = t & 63;
    const int G    = lane >> 4;
    const int q16  = lane & 15;
    const int h  = blockIdx.y;
    const int b  = blockIdx.z;
    const int bh = b * H_ + h;
    const int n0 = blockIdx.x * 64;
    const int nrow = min(n0 + w * 16 + q16, N_ - 1);

    bf16x8 qfh[2], qfl[2];
    {
        const size_t qb = ((size_t)bh * N_ + nrow) * D_ + 8 * G;
        #pragma unroll
        for (int dc = 0; dc < 2; ++dc) {
            qfh[dc] = *(const bf16x8*)(QH + qb + 32 * dc);
            qfl[dc] = *(const bf16x8*)(QL + qb + 32 * dc);
        }
    }

    const float* rpr = RPBP + (size_t)(h * N_ + nrow) * MP_;
    const float* mbr = MBp + b * MP_;

    // staging geometry: rep0 rows 0..31, rep1 rows 32..63; same chunk/swizzle
    const int mm0 = t >> 3;
    const int ch0 = t & 7;
    const int swz = (ch0 ^ (mm0 & 7)) << 3;
    const size_t kB = (size_t)bh * M_ * D_;
    const size_t vB = (size_t)bh * (D_ * VTP_);

    uint4 rkh0, rkh1, rkl0, rkl1, rvh0, rvh1, rvl0, rvl1;
    {   // prefetch tile 0
        const size_t kg0 = kB + (size_t)mm0 * D_ + ch0 * 8;
        const size_t vg0 = vB + (size_t)mm0 * VTP_ + ch0 * 8;
        rkh0 = *(const uint4*)(KH + kg0);  rkh1 = *(const uint4*)(KH + kg0 + 32 * D_);
        rkl0 = *(const uint4*)(KL + kg0);  rkl1 = *(const uint4*)(KL + kg0 + 32 * D_);
        rvh0 = *(const uint4*)(VTH + vg0); rvh1 = *(const uint4*)(VTH + vg0 + 32 * VTP_);
        rvl0 = *(const uint4*)(VTL + vg0); rvl1 = *(const uint4*)(VTL + vg0 + 32 * VTP_);
    }

    f32x4 o[4] = {};
    float m_run = -__builtin_inff();
    float l_run = 0.f;

    for (int m0 = 0; m0 < M_; m0 += 64) {
        __syncthreads();   // prev readers done (drains prefetch vmcnt -> store-ready)
        {   // store staged regs -> LDS (XOR-swizzled)
            const int l0 = mm0 * 64 + swz, l1 = l0 + 32 * 64;
            *(uint4*)&sKh[l0] = rkh0; *(uint4*)&sKh[l1] = rkh1;
            *(uint4*)&sKl[l0] = rkl0; *(uint4*)&sKl[l1] = rkl1;
            *(uint4*)&sVh[l0] = rvh0; *(uint4*)&sVh[l1] = rvh1;
            *(uint4*)&sVl[l0] = rvl0; *(uint4*)&sVl[l1] = rvl1;
        }
        if (m0 + 64 < M_) {   // prefetch next tile (latency hides under compute)
            const size_t kg0 = kB + (size_t)(m0 + 64 + mm0) * D_ + ch0 * 8;
            const size_t vg0 = vB + (size_t)mm0 * VTP_ + (m0 + 64) + ch0 * 8;
            rkh0 = *(const uint4*)(KH + kg0);  rkh1 = *(const uint4*)(KH + kg0 + 32 * D_);
            rkl0 = *(const uint4*)(KL + kg0);  rkl1 = *(const uint4*)(KL + kg0 + 32 * D_);
            rvh0 = *(const uint4*)(VTH + vg0); rvh1 = *(const uint4*)(VTH + vg0 + 32 * VTP_);
            rvl0 = *(const uint4*)(VTL + vg0); rvl1 = *(const uint4*)(VTL + vg0 + 32 * VTP_);
        }
        // make ds_writes visible WITHOUT draining vmcnt (keeps prefetch in flight)
        asm volatile("s_waitcnt lgkmcnt(0)" ::: "memory");
        __builtin_amdgcn_sched_barrier(0);
        __builtin_amdgcn_s_barrier();
        __builtin_amdgcn_sched_barrier(0);

        // ---- S^T = K.Q^T ----
        f32x4 s[4] = {};
        #pragma unroll
        for (int tt = 0; tt < 4; ++tt) {
            const int row = tt * 16 + q16;
            #pragma unroll
            for (int dc = 0; dc < 2; ++dc) {
                const int off = row * 64 + (((4 * dc + G) ^ (lane & 7)) << 3);
                bf16x8 kh = *(const bf16x8*)&sKh[off];
                bf16x8 kl = *(const bf16x8*)&sKl[off];
                s[tt] = __builtin_amdgcn_mfma_f32_16x16x32_bf16(kh, qfh[dc], s[tt], 0, 0, 0);
                s[tt] = __builtin_amdgcn_mfma_f32_16x16x32_bf16(kh, qfl[dc], s[tt], 0, 0, 0);
                s[tt] = __builtin_amdgcn_mfma_f32_16x16x32_bf16(kl, qfh[dc], s[tt], 0, 0, 0);
            }
        }

        // ---- bias + mask: padded tables, aligned float4, branch-free ----
        #pragma unroll
        for (int tt = 0; tt < 4; ++tt) {
            const int mc = m0 + tt * 16 + 4 * G;   // <= 959 < MP_
            const float4 rv = *(const float4*)(rpr + mc);
            const float4 mb = *(const float4*)(mbr + mc);
            s[tt][0] += rv.x + mb.x;
            s[tt][1] += rv.y + mb.y;
            s[tt][2] += rv.z + mb.z;
            s[tt][3] += rv.w + mb.w;
        }

        // ---- online softmax ----
        float tmax = -__builtin_inff();
        #pragma unroll
        for (int tt = 0; tt < 4; ++tt)
            #pragma unroll
            for (int v = 0; v < 4; ++v) tmax = fmaxf(tmax, s[tt][v]);
        tmax = fmaxf(tmax, __shfl_xor(tmax, 16, 64));
        tmax = fmaxf(tmax, __shfl_xor(tmax, 32, 64));
        const float m_new = fmaxf(m_run, tmax);
        const float corr  = __expf(m_run - m_new);
        float lsum = 0.f;
        #pragma unroll
        for (int tt = 0; tt < 4; ++tt)
            #pragma unroll
            for (int v = 0; v < 4; ++v) {
                const float p = __expf(s[tt][v] - m_new);
                s[tt][v] = p;
                lsum += p;
            }
        lsum += __shfl_xor(lsum, 16, 64);
        lsum += __shfl_xor(lsum, 32, 64);
        l_run = l_run * corr + lsum;
        m_run = m_new;
        float cr[4];
        #pragma unroll
        for (int v = 0; v < 4; ++v) cr[v] = __shfl(corr, 4 * G + v, 64);
        #pragma unroll
        for (int dt = 0; dt < 4; ++dt)
            #pragma unroll
            for (int v = 0; v < 4; ++v) o[dt][v] *= cr[v];

        // ---- PV: shfl-redistribute P into A-frags, 2 m-chunks ----
        #pragma unroll
        for (int c = 0; c < 2; ++c) {
            bf16x8 pah, pal;
            #pragma unroll
            for (int j = 0; j < 8; ++j) {
                const int srcLane = q16 + 16 * (2 * (G & 1) + (j >> 2));
                const float va = __shfl(s[2 * c][j & 3],     srcLane, 64);
                const float vb = __shfl(s[2 * c + 1][j & 3], srcLane, 64);
                const float val = (G < 2) ? va : vb;
                const bf16_t hh2 = (bf16_t)val;
                pah[j] = hh2;
                pal[j] = (bf16_t)(val - (float)hh2);
            }
            #pragma unroll
            for (int dt = 0; dt < 4; ++dt) {
                const int drow = dt * 16 + q16;
                const int off = drow * 64 + (((4 * c + G) ^ (lane & 7)) << 3);
                bf16x8 vh = *(const bf16x8*)&sVh[off];
                bf16x8 vl = *(const bf16x8*)&sVl[off];
                o[dt] = __builtin_amdgcn_mfma_f32_16x16x32_bf16(pah, vh, o[dt], 0, 0, 0);
                o[dt] = __builtin_amdgcn_mfma_f32_16x16x32_bf16(pah, vl, o[dt], 0, 0, 0);
                o[dt] = __builtin_amdgcn_mfma_f32_16x16x32_bf16(pal, vh, o[dt], 0, 0, 0);
            }
        }
    }

    // ---- epilogue: normalize + bf16 hi/lo store ----
    float linv[4];
    #pragma unroll
    for (int v = 0; v < 4; ++v) linv[v] = 1.f / __shfl(l_run, 4 * G + v, 64);
    const int nb = n0 + w * 16;
    #pragma unroll
    for (int dt = 0; dt < 4; ++dt) {
        #pragma unroll
        for (int v = 0; v < 4; ++v) {
            const int n = nb + 4 * G + v;
            if (n < N_) {
                const size_t oi = ((size_t)b * N_ + n) * C_ + h * D_ + dt * 16 + q16;
                bf16_t hi, lo;
                bsplit(o[dt][v] * linv[v], hi, lo);
                ATTH[oi] = hi; ATTL[oi] = lo;
            }
        }
    }
}

// ---------------------------------------------------------------------------
extern "C" void kernel_launch(void* const* d_in, const int* in_sizes, int n_in,
                              void* d_out, int out_size, void* d_ws, size_t ws_size,
                              hipStream_t stream)
{
    const float* x         = (const float*)d_in[0];
    const float* mask      = (const float*)d_in[1];
    const float* rpb       = (const float*)d_in[2];
    const float* qkv_w     = (const float*)d_in[3];
    const float* q_bias    = (const float*)d_in[4];
    const float* v_bias    = (const float*)d_in[5];
    const float* proj_w    = (const float*)d_in[6];
    const float* proj_b    = (const float*)d_in[7];
    const float* text_emb  = (const float*)d_in[8];
    const float* image_emb = (const float*)d_in[9];
    const float* pp_w1     = (const float*)d_in[10];
    const float* pp_b1     = (const float*)d_in[11];
    const float* pp_w2     = (const float*)d_in[12];
    const float* pp_b2     = (const float*)d_in[13];
    float* out = (float*)d_out;

    char* w8 = (char*)d_ws;
    auto alloc = [&](size_t bytes) -> char* {
        char* p = w8; w8 += (bytes + 255) & ~(size_t)255; return p;
    };
    const size_t Q_ELT  = (size_t)B_ * H_ * N_ * D_;            // 9,498,624
    const size_t K_ELT  = (size_t)B_ * H_ * M_ * D_ + 8192;     // + attn tile-overrun slack
    const size_t VT_ELT = (size_t)B_ * H_ * D_ * VTP_;          // 11,796,480
    const size_t X_ELT  = (size_t)GMP_ * C_;                    // 9,535,488 (padded rows)

    bf16_t* QH  = (bf16_t*)alloc(Q_ELT * 2);
    bf16_t* QL  = (bf16_t*)alloc(Q_ELT * 2);
    bf16_t* KH  = (bf16_t*)alloc(K_ELT * 2);
    bf16_t* KL  = (bf16_t*)alloc(K_ELT * 2);
    bf16_t* VTH = (bf16_t*)alloc(VT_ELT * 2);
    bf16_t* VTL = (bf16_t*)alloc(VT_ELT * 2);
    bf16_t* XH  = (bf16_t*)alloc(X_ELT * 2);   // reused as ATTH after QKV GEMM
    bf16_t* XL  = (bf16_t*)alloc(X_ELT * 2);   // reused as ATTL
    bf16_t* QWH = (bf16_t*)alloc((size_t)3 * C_ * C_ * 2);
    bf16_t* QWL = (bf16_t*)alloc((size_t)3 * C_ * C_ * 2);
    bf16_t* PWH = (bf16_t*)alloc((size_t)C_ * C_ * 2);
    bf16_t* PWL = (bf16_t*)alloc((size_t)C_ * C_ * 2);
    float*  RPBP = (float*)alloc((size_t)H_ * N_ * MP_ * 4);
    float*  MBp  = (float*)alloc((size_t)B_ * MP_ * 4);
    float*  Hb   = (float*)alloc((size_t)2 * P_ * C_ * 4);
    float*  P2   = (float*)alloc((size_t)2 * P_ * 2 * C_ * 4);
    (void)ws_size; (void)in_sizes; (void)n_in; (void)out_size;

    // input splits (fp32 -> bf16 hi/lo)
    split4<<<(GM_ * C_ / 4 + 255) / 256, 256, 0, stream>>>(x, XH, XL, GM_ * C_ / 4);
    split4<<<(3 * C_ * C_ / 4 + 255) / 256, 256, 0, stream>>>(qkv_w, QWH, QWL, 3 * C_ * C_ / 4);
    split4<<<(C_ * C_ / 4 + 255) / 256, 256, 0, stream>>>(proj_w, PWH, PWL, C_ * C_ / 4);

    // prompt MLP (batch-independent) + prefix scatter
    prompt_h<<<(2 * P_ * C_) / 256, 256, 0, stream>>>(text_emb, image_emb, pp_w1, pp_b1, Hb);
    prompt_p2<<<(2 * P_ * 2 * C_) / 256, 256, 0, stream>>>(Hb, pp_w2, pp_b2, P2);
    scatter_prompts<<<(2 * P_ * C_) / 256, 256, 0, stream>>>(P2, KH, KL, VTH, VTL);

    // bias tables
    build_rpbp<<<(H_ * N_ * MP_) / 256, 256, 0, stream>>>(rpb, RPBP);
    build_mb<<<(B_ * MP_) / 256, 256, 0, stream>>>(mask, MBp);

    // QKV GEMM (MFMA bf16x3) -> Q/K/VT scatter
    gemm_mfma<1><<<dim3(GMP_ / 128, 3 * C_ / 128), 256, 0, stream>>>(
        XH, XL, QWH, QWL, q_bias, v_bias, nullptr,
        QH, QL, KH, KL, VTH, VTL);

    // attention (writes ATTH/ATTL over XH/XL — stream-ordered after QKV GEMM)
    attn_mfma<<<dim3((N_ + 63) / 64, H_, B_), 256, 0, stream>>>(
        QH, QL, KH, KL, VTH, VTL, RPBP, MBp, XH, XL);

    // output projection (MFMA bf16x3)
    gemm_mfma<0><<<dim3(GMP_ / 128, C_ / 128), 256, 0, stream>>>(
        XH, XL, PWH, PWL, proj_b, nullptr, out,
        nullptr, nullptr, nullptr, nullptr, nullptr, nullptr);
}